// Round 7
// baseline (129.634 us; speedup 1.0000x reference)
//
#include <hip/hip_runtime.h>

// DynamiConv via implicit-im2col f16 MFMA.
// R1: A-pack staged to LDS -> removed 18 in-loop global A fetches (-7.5us).
// R2: gate via v_dot2_f32_f16 on packed dW; gpart f16; LDS diet (-3us).
// R3: TH=8 tile (512 thr): halo/interior 1.59->1.33 (-3.5us). 42us.
// R4/R5: NT=4 intra-block pipeline REGRESSED (spill; then 2/CU grid tail).
// R6: vmcnt(0) fence for single-round-trip staging: VGPR=40 = v[32]+addr,
//   so staging was already ~1 round trip; ~flat. Counters: pipes ~36% busy,
//   Occ 43% vs 75% cap -> CONVOY latency-bound; lever = waves in flight.
// R7: TH=16 mega-tile: 1024 thr / 16 waves, tile 16x32.
//   halo/interior 612/512 = 1.20 (vs 1.33, -10% staging per output);
//   LDS 74312 B -> 2 blocks/CU = 32 waves = 100% wave cap (was 75%).
//   launch_bounds(1024,8) caps VGPR at 64 (R6 measured 40 for the same
//   staging structure -> headroom, no spill expected). A-copy = exactly one
//   half8 per thread. Grid 1024 = 2 residency rounds.
// x[8,32,256,256] f32, W[32,32,3,3], dW[1,32,3,3], bias[32] -> out[8,32,256,256] f32

typedef _Float16 half8 __attribute__((ext_vector_type(8)));
typedef _Float16 half2 __attribute__((ext_vector_type(2)));
typedef float f32x16 __attribute__((ext_vector_type(16)));

#define BATCH 8
#define CIN 32
#define COUT 32
#define TW 32           // spatial tile width (one MFMA n-tile)
#define TH 16           // spatial tile height: 16 rows, 1 per wave, 1024 thr
#define HTW 34
#define HTH 18
#define CSTR 40         // f16 per position (32 ch + 8 pad) = 80 B stride
#define NCHUNK 18       // K=288 as 18 chunks of 16
#define NLDSA 14        // A chunks staged in LDS; chunks 14..17 live in VGPRs
#define NREGA (NCHUNK - NLDSA)
#define NPOS (HTH*HTW)  // 612 halo positions (one owner thread each)

// Apack = W in per-lane MFMA A order (o=lane&31, c=(q&1)*16+(lane>>5)*8+j, tap=q>>1).
// dwf2[cp][tap] = (dW[2cp][tap], dW[2cp+1][tap]) f16x2, tap-minor.
__global__ __launch_bounds__(256) void prep_pack(const float* __restrict__ w,
                                                 const float* __restrict__ dw,
                                                 _Float16* __restrict__ Apack,
                                                 half2* __restrict__ dwf2) {
  int t = blockIdx.x * 256 + threadIdx.x;
  if (t < 9216) {
    int q = t >> 9, lane = (t >> 3) & 63, j = t & 7;
    int tap = q >> 1, h = q & 1;
    int o = lane & 31, lh = lane >> 5;
    int c = h * 16 + lh * 8 + j;
    Apack[t] = (_Float16)w[o * 288 + c * 9 + tap];
  } else if (t < 9216 + 144) {
    int i = t - 9216;          // i = cp*9 + tap
    int cp = i / 9, tap = i - cp * 9;
    half2 d;
    d.x = (_Float16)dw[(2 * cp) * 9 + tap];
    d.y = (_Float16)dw[(2 * cp + 1) * 9 + tap];
    dwf2[i] = d;
  }
}

__global__ __launch_bounds__(1024, 8) void dynconv(
    const float* __restrict__ x, const _Float16* __restrict__ Apack,
    const half2* __restrict__ dwf2, const float* __restrict__ bias,
    float* __restrict__ out) {
  __shared__ __align__(16) _Float16 lvA[NLDSA * 512];  // 14336 B: A chunks 0..13
  __shared__ __align__(16) _Float16 lv[NPOS * CSTR];   // 48960 B f16 values
  __shared__ _Float16 gpart[9 * NPOS];                 // 11016 B gate tap-partials

  // XCD-batch swizzle: XCD k handles batch k; halo re-reads stay in its L2.
  const int bid0 = blockIdx.x;              // grid = 1024
  const int bb = bid0 & 7, idx = bid0 >> 3;
  const int xt = idx & 7, yt = idx >> 3;    // yt < 16
  const int x0 = xt * TW, y0 = yt * TH;
  const int tid = threadIdx.x;
  const int lane = tid & 63;

  // ---- A-pack chunks 0..13 -> LDS: 896 half8 units, one per thread ----
  half8 acopy;
  if (tid < NLDSA * 64)
    acopy = *(const half8*)(Apack + (tid << 3));

  // ---- staging: one owner thread per halo position ----
  const bool owner = tid < NPOS;
  float v[CIN];
  if (owner) {
    const int yy = tid / HTW, xx = tid - (tid / HTW) * HTW;
    const int gy = y0 + yy - 1, gx = x0 + xx - 1;
    const int voff = (gy << 8) + gx;        // uniform across c -> saddr-form loads
    if ((unsigned)gy < 256u && (unsigned)gx < 256u) {
#pragma unroll
      for (int c = 0; c < CIN; ++c)
        v[c] = x[(((size_t)(bb * CIN + c)) << 16) + voff];  // 32-deep MLP
    } else {
#pragma unroll
      for (int c = 0; c < CIN; ++c) v[c] = 0.f;
    }
  }

  // A-pack LDS write (counted vmcnt: waits acopy only, x loads stay in flight)
  if (tid < NLDSA * 64)
    *(half8*)(lvA + (tid << 3)) = acopy;

  // Single-round-trip fence: all 32 x-loads complete here, all live at once.
  asm volatile("s_waitcnt vmcnt(0)" ::: "memory");

  if (owner) {
    float p[9];
#pragma unroll
    for (int tap = 0; tap < 9; ++tap) p[tap] = 0.f;
    _Float16 hv[CIN];
#pragma unroll
    for (int cp = 0; cp < CIN / 2; ++cp) {
      const float v0 = v[2 * cp], v1 = v[2 * cp + 1];
      const float s0 = __builtin_amdgcn_rcpf(1.f + __expf(-v0));
      const float s1 = __builtin_amdgcn_rcpf(1.f + __expf(-v1));
      half2 s2;
      s2.x = (_Float16)s0;
      s2.y = (_Float16)s1;
      hv[2 * cp] = (_Float16)v0;
      hv[2 * cp + 1] = (_Float16)v1;
#pragma unroll
      for (int tap = 0; tap < 9; ++tap) {
        const half2 d2 = dwf2[cp * 9 + tap];   // uniform -> SGPR operand
#if __has_builtin(__builtin_amdgcn_fdot2)
        p[tap] = __builtin_amdgcn_fdot2(s2, d2, p[tap], false);
#else
        p[tap] += (float)s2.x * (float)d2.x + (float)s2.y * (float)d2.y;
#endif
      }
    }
#pragma unroll
    for (int u = 0; u < 4; ++u)
      *(half8*)(lv + tid * CSTR + u * 8) = *(const half8*)(hv + u * 8);
#pragma unroll
    for (int tap = 0; tap < 9; ++tap)
      gpart[tap * NPOS + tid] = (_Float16)p[tap];  // exclusive owner: plain ds_write
  }

  // ---- A-pack register chunks 14..17: issued after staging so their regs
  // aren't live through it; latency hides under barrier + gate compute.
  half8 areg[NREGA];
#pragma unroll
  for (int r = 0; r < NREGA; ++r)
    areg[r] = *(const half8*)(Apack + (((NLDSA + r) * 64 + lane) << 3));

  __syncthreads();

  // ---- compute: wave w8 owns tile row y0+w8; 18 chunks, 1 MFMA each ----
  const int w8 = tid >> 6;                  // w8 in 0..15
  const int ln = lane & 31, lh = lane >> 5;

  float gate = 0.f;
#pragma unroll
  for (int ki = 0; ki < 3; ++ki)
#pragma unroll
    for (int kj = 0; kj < 3; ++kj)
      gate += (float)gpart[(ki * 3 + kj) * NPOS + (w8 + ki) * HTW + ln + kj];

  f32x16 acc;
#pragma unroll
  for (int i = 0; i < 16; ++i) acc[i] = 0.f;

#pragma unroll
  for (int q = 0; q < NCHUNK; ++q) {
    const int tap = q >> 1, h = q & 1;
    const int ki = tap / 3, kj = tap - ki * 3;
    const half8 a = (q < NLDSA)
                        ? *(const half8*)(lvA + ((q * 64 + lane) << 3))  // LDS, lane-linear
                        : areg[q - NLDSA];                               // VGPR-resident
    const int off = ((w8 + ki) * HTW + ln + kj) * CSTR + h * 16 + lh * 8;
    const half8 bv = *(const half8*)(lv + off);   // ds_read_b128
    acc = __builtin_amdgcn_mfma_f32_32x32x16_f16(a, bv, acc, 0, 0, 0);
  }

  // ---- epilogue: D layout col=lane&31, row=(reg&3)+8*(reg>>2)+4*(lane>>5) ----
  const int voff_out = ((y0 + w8) << 8) + x0 + ln;
#pragma unroll
  for (int reg = 0; reg < 16; ++reg) {
    const int o = (reg & 3) + 8 * (reg >> 2) + 4 * lh;
    out[(((size_t)(bb * COUT + o)) << 16) + voff_out] = acc[reg] * gate + bias[o];
  }
}

extern "C" void kernel_launch(void* const* d_in, const int* in_sizes, int n_in,
                              void* d_out, int out_size, void* d_ws, size_t ws_size,
                              hipStream_t stream) {
  const float* x    = (const float*)d_in[0];
  const float* wgt  = (const float*)d_in[1];
  const float* dw   = (const float*)d_in[2];
  const float* bias = (const float*)d_in[3];
  float* out = (float*)d_out;

  _Float16* Apack = (_Float16*)d_ws;                  // 9216 f16 = 18432 B
  half2* dwf2     = (half2*)((char*)d_ws + 18432);    // 144 half2 = 576 B

  prep_pack<<<(9216 + 144 + 255) / 256, 256, 0, stream>>>(wgt, dw, Apack, dwf2);
  dynconv<<<BATCH * (256 / TH) * (256 / TW), 1024, 0, stream>>>(x, Apack, dwf2, bias, out);
}

// Round 9
// 128.088 us; speedup vs baseline: 1.0121x; 1.0121x over previous
//
#include <hip/hip_runtime.h>

// DynamiConv via implicit-im2col f16 MFMA.
// R1: A-pack staged to LDS -> removed 18 in-loop global A fetches (-7.5us).
// R2: gate via v_dot2_f32_f16 on packed dW; gpart f16; LDS diet (-3us).
// R3: TH=8 tile (512 thr): halo/interior 1.59->1.33 (-3.5us). 42us.
// R4/R5: NT=4 intra-block pipeline REGRESSED (spill; grid tail). Abandoned.
// R6: vmcnt(0) fence -- INEFFECTIVE: VGPR=40 shows sigma chunks were hoisted
//   ABOVE the fence (pure-ALU ops may move up past a memory clobber), so
//   staging stayed ~6 serialized round-trips.
// R7: TH=16 mega-tile (1024 thr, 2 blocks/CU = 100% wave cap): Occ 43->59,
//   dur FLAT 42.5, VGPR=32 -> fence still not engaging; plateau = the
//   untouched serialized staging path.
// R8: register PINS make the fence real: after vmcnt(0), each v[c] passes
//   through asm("" : "+v") -- pins are volatile (ordered after the fence),
//   "+v" redefines v[c] so no consumer hoists above, loads can't sink below
//   the memory clobber -> all 32 loads in flight at once, ONE round-trip.
//   Peak regs ~55 < cap 64 (launch_bounds(1024,8)): no spill expected.
//   (R8 bench: container infra failure, no data -> resubmitted unchanged.)
// x[8,32,256,256] f32, W[32,32,3,3], dW[1,32,3,3], bias[32] -> out[8,32,256,256] f32

typedef _Float16 half8 __attribute__((ext_vector_type(8)));
typedef _Float16 half2 __attribute__((ext_vector_type(2)));
typedef float f32x16 __attribute__((ext_vector_type(16)));

#define BATCH 8
#define CIN 32
#define COUT 32
#define TW 32           // spatial tile width (one MFMA n-tile)
#define TH 16           // spatial tile height: 16 rows, 1 per wave, 1024 thr
#define HTW 34
#define HTH 18
#define CSTR 40         // f16 per position (32 ch + 8 pad) = 80 B stride
#define NCHUNK 18       // K=288 as 18 chunks of 16
#define NLDSA 14        // A chunks staged in LDS; chunks 14..17 live in VGPRs
#define NREGA (NCHUNK - NLDSA)
#define NPOS (HTH*HTW)  // 612 halo positions (one owner thread each)

// Apack = W in per-lane MFMA A order (o=lane&31, c=(q&1)*16+(lane>>5)*8+j, tap=q>>1).
// dwf2[cp][tap] = (dW[2cp][tap], dW[2cp+1][tap]) f16x2, tap-minor.
__global__ __launch_bounds__(256) void prep_pack(const float* __restrict__ w,
                                                 const float* __restrict__ dw,
                                                 _Float16* __restrict__ Apack,
                                                 half2* __restrict__ dwf2) {
  int t = blockIdx.x * 256 + threadIdx.x;
  if (t < 9216) {
    int q = t >> 9, lane = (t >> 3) & 63, j = t & 7;
    int tap = q >> 1, h = q & 1;
    int o = lane & 31, lh = lane >> 5;
    int c = h * 16 + lh * 8 + j;
    Apack[t] = (_Float16)w[o * 288 + c * 9 + tap];
  } else if (t < 9216 + 144) {
    int i = t - 9216;          // i = cp*9 + tap
    int cp = i / 9, tap = i - cp * 9;
    half2 d;
    d.x = (_Float16)dw[(2 * cp) * 9 + tap];
    d.y = (_Float16)dw[(2 * cp + 1) * 9 + tap];
    dwf2[i] = d;
  }
}

__global__ __launch_bounds__(1024, 8) void dynconv(
    const float* __restrict__ x, const _Float16* __restrict__ Apack,
    const half2* __restrict__ dwf2, const float* __restrict__ bias,
    float* __restrict__ out) {
  __shared__ __align__(16) _Float16 lvA[NLDSA * 512];  // 14336 B: A chunks 0..13
  __shared__ __align__(16) _Float16 lv[NPOS * CSTR];   // 48960 B f16 values
  __shared__ _Float16 gpart[9 * NPOS];                 // 11016 B gate tap-partials

  // XCD-batch swizzle: XCD k handles batch k; halo re-reads stay in its L2.
  const int bid0 = blockIdx.x;              // grid = 1024
  const int bb = bid0 & 7, idx = bid0 >> 3;
  const int xt = idx & 7, yt = idx >> 3;    // yt < 16
  const int x0 = xt * TW, y0 = yt * TH;
  const int tid = threadIdx.x;
  const int lane = tid & 63;

  // ---- A-pack chunks 0..13 -> LDS: 896 half8 units, one per thread ----
  half8 acopy;
  if (tid < NLDSA * 64)
    acopy = *(const half8*)(Apack + (tid << 3));

  // ---- staging: one owner thread per halo position ----
  const bool owner = tid < NPOS;
  float v[CIN];
  if (owner) {
    const int yy = tid / HTW, xx = tid - (tid / HTW) * HTW;
    const int gy = y0 + yy - 1, gx = x0 + xx - 1;
    const int voff = (gy << 8) + gx;        // uniform across c -> saddr-form loads
    if ((unsigned)gy < 256u && (unsigned)gx < 256u) {
#pragma unroll
      for (int c = 0; c < CIN; ++c)
        v[c] = x[(((size_t)(bb * CIN + c)) << 16) + voff];  // 32-deep MLP
    } else {
#pragma unroll
      for (int c = 0; c < CIN; ++c) v[c] = 0.f;
    }
  }

  // A-pack LDS write (waits acopy only; x loads stay in flight until fence)
  if (tid < NLDSA * 64)
    *(half8*)(lvA + (tid << 3)) = acopy;

  // TRUE single-round-trip fence: loads can't sink below the memory clobber;
  // the pins below are volatile (ordered after it) and redefine each v[c],
  // so no ALU consumer can hoist above -> all 32 loads outstanding at once.
  asm volatile("s_waitcnt vmcnt(0)" ::: "memory");

  if (owner) {
#pragma unroll
    for (int c = 0; c < CIN; ++c)
      asm volatile("" : "+v"(v[c]));        // liveness pin

    float p[9];
#pragma unroll
    for (int tap = 0; tap < 9; ++tap) p[tap] = 0.f;
    _Float16 hv[CIN];
#pragma unroll
    for (int cp = 0; cp < CIN / 2; ++cp) {
      const float v0 = v[2 * cp], v1 = v[2 * cp + 1];
      const float s0 = __builtin_amdgcn_rcpf(1.f + __expf(-v0));
      const float s1 = __builtin_amdgcn_rcpf(1.f + __expf(-v1));
      half2 s2;
      s2.x = (_Float16)s0;
      s2.y = (_Float16)s1;
      hv[2 * cp] = (_Float16)v0;
      hv[2 * cp + 1] = (_Float16)v1;
#pragma unroll
      for (int tap = 0; tap < 9; ++tap) {
        const half2 d2 = dwf2[cp * 9 + tap];   // uniform -> SGPR operand
#if __has_builtin(__builtin_amdgcn_fdot2)
        p[tap] = __builtin_amdgcn_fdot2(s2, d2, p[tap], false);
#else
        p[tap] += (float)s2.x * (float)d2.x + (float)s2.y * (float)d2.y;
#endif
      }
    }
#pragma unroll
    for (int u = 0; u < 4; ++u)
      *(half8*)(lv + tid * CSTR + u * 8) = *(const half8*)(hv + u * 8);
#pragma unroll
    for (int tap = 0; tap < 9; ++tap)
      gpart[tap * NPOS + tid] = (_Float16)p[tap];  // exclusive owner: plain ds_write
  }

  // ---- A-pack register chunks 14..17: issued after staging so their regs
  // aren't live through it; latency hides under barrier + gate compute.
  half8 areg[NREGA];
#pragma unroll
  for (int r = 0; r < NREGA; ++r)
    areg[r] = *(const half8*)(Apack + (((NLDSA + r) * 64 + lane) << 3));

  __syncthreads();

  // ---- compute: wave w8 owns tile row y0+w8; 18 chunks, 1 MFMA each ----
  const int w8 = tid >> 6;                  // w8 in 0..15
  const int ln = lane & 31, lh = lane >> 5;

  float gate = 0.f;
#pragma unroll
  for (int ki = 0; ki < 3; ++ki)
#pragma unroll
    for (int kj = 0; kj < 3; ++kj)
      gate += (float)gpart[(ki * 3 + kj) * NPOS + (w8 + ki) * HTW + ln + kj];

  f32x16 acc;
#pragma unroll
  for (int i = 0; i < 16; ++i) acc[i] = 0.f;

#pragma unroll
  for (int q = 0; q < NCHUNK; ++q) {
    const int tap = q >> 1, h = q & 1;
    const int ki = tap / 3, kj = tap - ki * 3;
    const half8 a = (q < NLDSA)
                        ? *(const half8*)(lvA + ((q * 64 + lane) << 3))  // LDS, lane-linear
                        : areg[q - NLDSA];                               // VGPR-resident
    const int off = ((w8 + ki) * HTW + ln + kj) * CSTR + h * 16 + lh * 8;
    const half8 bv = *(const half8*)(lv + off);   // ds_read_b128
    acc = __builtin_amdgcn_mfma_f32_32x32x16_f16(a, bv, acc, 0, 0, 0);
  }

  // ---- epilogue: D layout col=lane&31, row=(reg&3)+8*(reg>>2)+4*(lane>>5) ----
  const int voff_out = ((y0 + w8) << 8) + x0 + ln;
#pragma unroll
  for (int reg = 0; reg < 16; ++reg) {
    const int o = (reg & 3) + 8 * (reg >> 2) + 4 * lh;
    out[(((size_t)(bb * COUT + o)) << 16) + voff_out] = acc[reg] * gate + bias[o];
  }
}

extern "C" void kernel_launch(void* const* d_in, const int* in_sizes, int n_in,
                              void* d_out, int out_size, void* d_ws, size_t ws_size,
                              hipStream_t stream) {
  const float* x    = (const float*)d_in[0];
  const float* wgt  = (const float*)d_in[1];
  const float* dw   = (const float*)d_in[2];
  const float* bias = (const float*)d_in[3];
  float* out = (float*)d_out;

  _Float16* Apack = (_Float16*)d_ws;                  // 9216 f16 = 18432 B
  half2* dwf2     = (half2*)((char*)d_ws + 18432);    // 144 half2 = 576 B

  prep_pack<<<(9216 + 144 + 255) / 256, 256, 0, stream>>>(wgt, dw, Apack, dwf2);
  dynconv<<<BATCH * (256 / TH) * (256 / TW), 1024, 0, stream>>>(x, Apack, dwf2, bias, out);
}